// Round 9
// baseline (854.327 us; speedup 1.0000x reference)
//
#include <hip/hip_runtime.h>
#include <cstdint>
#include <cfloat>

// ---------------------------------------------------------------------------
// SimpleVQVAEEncoder, round 11: transposed-operand implicit GEMM (lane = oc).
// Diagnosis across R2/R6/R8: the conv stall is the wave-uniform weight
// s_load stream (SGPR-capped prefetch, 16 waves convoying on ~250-cyc
// scalar latency). Fix: weights go to LDS (Ws[BK][OC], coalesced per-lane
// ds_read_b32); pixels become the broadcast operand (uniform ds_read_b128).
// No s_load in the K-loop at all. All conv outputs stored oc-major [oc][pix]
// (per-lane float4 stores); inputs read ic-major via template strides.
// Same proven 2-barrier skeleton; no pipelining (R1/R4/R5), no redundant
// staging (R2/R8), direct static LDS indexing only.
// ---------------------------------------------------------------------------

constexpr int B_    = 128;
constexpr int HW3   = 169;
constexpr int NPIXT = B_ * HW3;        // 21632
constexpr int NEMB  = 512;
constexpr int EMB   = 64;

// transpose weights [OC][K] -> [K][OC] (tiny prepass)
__global__ __launch_bounds__(256) void wtrans_kernel(
    const float* __restrict__ w, float* __restrict__ wt, int OC, int K)
{
    int idx = blockIdx.x * 256 + threadIdx.x;
    if (idx >= OC * K) return;
    int oc = idx / K, k = idx - oc * K;
    wt[(size_t)k * OC + oc] = w[idx];
}

// in  : ic-major via NSTRIDE/ICSTRIDE (x is n-major: NSTRIDE=IC*IH*IW)
// out : [OC][OPIX] oc-major, pix = n*OH*OW + oy*OW + ox (linear)
template<int IC, int OC, int KH, int KW, int IH, int IW, int OH, int OW,
         int STRIDE, int PAD, bool RELU, int NSTRIDE, int ICSTRIDE,
         int OPIX, int PIXPW>
__global__ __launch_bounds__(512) void conv_tn(
    const float* __restrict__ in, const float* __restrict__ wt,   // wt: [K][OC]
    const float* __restrict__ bias, float* __restrict__ out)
{
    constexpr int K   = IC * KH * KW;
    constexpr int KHW = KH * KW;
    constexpr int BK  = 64;
    static_assert(K % BK == 0, "K must divide by BK");
    constexpr int SLICES = OC / 64;        // oc slices of 64 lanes
    constexpr int GROUPS = 8 / SLICES;     // pixel groups per block
    constexpr int MPX = GROUPS * PIXPW;    // pixels per block
    constexpr int HWo = OH * OW;
    static_assert(PIXPW % 4 == 0, "float4 epilogue");
    // MPX==32 staging path needs shift-only k-decomposition
    static_assert(MPX >= 64 || ((KHW & (KHW - 1)) == 0 && (KW & (KW - 1)) == 0));

    __shared__ float As[BK][MPX];          // pixel tile
    __shared__ float Ws[BK * OC];          // weight tile [kk][oc]

    const int tid  = threadIdx.x;
    const int lane = tid & 63;
    const int wv   = __builtin_amdgcn_readfirstlane(tid >> 6);  // uniform
    const int slice = wv % SLICES;
    const int pg    = wv / SLICES;
    const int oc    = slice * 64 + lane;
    const int pixbase = blockIdx.x * MPX;
    const int krow  = wv * (BK / 8);       // uniform LDS row base (staging)

    // ---- hoisted decomposition of the pixels THIS LANE stages ----
    constexpr int SPX = (MPX >= 64) ? MPX / 64 : 1;
    int nb[SPX], iyb[SPX], ixb[SPX];
#pragma unroll
    for (int m = 0; m < SPX; m++) {
        int px = (MPX >= 64) ? (pixbase + m * 64 + lane)
                             : (pixbase + (lane & 31));
        int n  = px / HWo;
        int hw = px - n * HWo;
        int oy = hw / OW;
        int ox = hw - oy * OW;
        nb[m]  = n * NSTRIDE;
        iyb[m] = oy * STRIDE - PAD;
        ixb[m] = ox * STRIDE - PAD;
    }

    float acc[PIXPW];
#pragma unroll
    for (int q = 0; q < PIXPW; q++) acc[q] = 0.f;

    for (int k0 = 0; k0 < K; k0 += BK) {
        __syncthreads();               // previous iter's reads done

        // ---- stage pixel tile (R3/R6 SALU k-decomposition) ----
        if constexpr (MPX >= 64) {
#pragma unroll
            for (int i = 0; i < (BK / 8) * SPX; i++) {
                int row = krow + i / SPX;            // uniform
                int m   = i % SPX;                   // uniform
                int k   = k0 + row;                  // uniform -> SALU decomp
                int ic = k / KHW;
                int r  = k - ic * KHW;
                int ky = r / KW;
                int kx = r - ky * KW;
                int iy = iyb[m] + ky;                // per-lane: 1 add
                int ix = ixb[m] + kx;                // 1 add
                float v = 0.f;
                if ((unsigned)iy < (unsigned)IH && (unsigned)ix < (unsigned)IW)
                    v = in[(size_t)ic * ICSTRIDE + nb[m] + iy * IW + ix];
                As[row][m * 64 + lane] = v;
            }
        } else {   // MPX == 32: two rows per iter via lane halves, shift decomp
#pragma unroll
            for (int i = 0; i < BK / 16; i++) {
                int row = krow + i * 2 + (lane >> 5);
                int k   = k0 + row;
                int ic = k / KHW;                    // KHW pow2 -> shifts
                int r  = k - ic * KHW;
                int ky = r / KW;
                int kx = r - ky * KW;
                int iy = iyb[0] + ky;
                int ix = ixb[0] + kx;
                float v = 0.f;
                if ((unsigned)iy < (unsigned)IH && (unsigned)ix < (unsigned)IW)
                    v = in[(size_t)ic * ICSTRIDE + nb[0] + iy * IW + ix];
                As[row][lane & 31] = v;
            }
        }

        // ---- stage weight tile (coalesced float4, L2-resident source) ----
        {
            const float4* wt4 = (const float4*)(wt + (size_t)k0 * OC);
#pragma unroll
            for (int s = 0; s < (BK * OC) / 2048; s++) {
                float4 v = wt4[s * 512 + tid];
                *(float4*)&Ws[(s * 512 + tid) * 4] = v;
            }
        }
        __syncthreads();

        // ---- FMA: weight per-lane b32, pixels broadcast b128 ----
#pragma unroll
        for (int kk = 0; kk < BK; kk++) {
            float w = Ws[kk * OC + oc];              // coalesced ds_read_b32
#pragma unroll
            for (int q = 0; q < PIXPW / 4; q++) {
                float4 p = *(const float4*)&As[kk][pg * PIXPW + q * 4];
                acc[q * 4 + 0] = fmaf(p.x, w, acc[q * 4 + 0]);
                acc[q * 4 + 1] = fmaf(p.y, w, acc[q * 4 + 1]);
                acc[q * 4 + 2] = fmaf(p.z, w, acc[q * 4 + 2]);
                acc[q * 4 + 3] = fmaf(p.w, w, acc[q * 4 + 3]);
            }
        }
    }

    // ---- epilogue: per-lane consecutive float4 stores, oc-major ----
    const float b = bias[oc];
    float* op = out + (size_t)oc * OPIX + pixbase + pg * PIXPW;
#pragma unroll
    for (int q = 0; q < PIXPW / 4; q++) {
        float4 v;
        v.x = acc[q * 4 + 0] + b;  v.y = acc[q * 4 + 1] + b;
        v.z = acc[q * 4 + 2] + b;  v.w = acc[q * 4 + 3] + b;
        if (RELU) {
            v.x = fmaxf(v.x, 0.f); v.y = fmaxf(v.y, 0.f);
            v.z = fmaxf(v.z, 0.f); v.w = fmaxf(v.w, 0.f);
        }
        *(float4*)&op[q * 4] = v;
    }
}

// ---------------------------------------------------------------------------
// VQ: per pixel argmin over 512 codes of |z|^2 - 2 z.c + |c|^2.
// z transposed [64][21632] -> coalesced loads. Codebook reads wave-uniform.
// ---------------------------------------------------------------------------
__global__ __launch_bounds__(256) void vq_kernel(
    const float* __restrict__ zt,           // [64][21632]
    const float* __restrict__ cb,           // [512][64]
    unsigned long long* __restrict__ best)  // [21632], preset to ~0
{
    const int tid  = threadIdx.x;
    const int lane = tid & 63;
    const int wv   = tid >> 6;
    const int pg   = blockIdx.x >> 1;
    const int half = blockIdx.x & 1;
    const int p    = pg * 64 + lane;        // 338*64 == 21632 exactly

    __shared__ float c2s[256];
    {
        int code = half * 256 + tid;
        const float* c = cb + (size_t)code * EMB;
        float s = 0.f;
#pragma unroll
        for (int j = 0; j < EMB; j += 4) {
            float4 v = *(const float4*)(c + j);
            s = fmaf(v.x, v.x, s); s = fmaf(v.y, v.y, s);
            s = fmaf(v.z, v.z, s); s = fmaf(v.w, v.w, s);
        }
        c2s[tid] = s;
    }
    __syncthreads();

    float zr[EMB];
    float zz = 0.f;
#pragma unroll
    for (int j = 0; j < EMB; j++) {
        float v = zt[(size_t)j * NPIXT + p];
        zr[j] = v;
        zz = fmaf(v, v, zz);
    }

    float bestScore = FLT_MAX;
    int   bestIdx   = 0x7fffffff;
    const int base = half * 256 + wv * 64;
    for (int ci = 0; ci < 64; ci++) {
        int code = __builtin_amdgcn_readfirstlane(base + ci);
        const float* c = cb + (size_t)code * EMB;
        float dot = 0.f;
#pragma unroll
        for (int j = 0; j < EMB; j++) dot = fmaf(zr[j], c[j], dot);
        float score = fmaf(-2.f, dot, zz) + c2s[code - half * 256];
        if (score < bestScore) { bestScore = score; bestIdx = code; }
    }

    unsigned u = __float_as_uint(bestScore);
    u = (bestScore < 0.f) ? ~u : (u | 0x80000000u);
    unsigned long long pk = ((unsigned long long)u << 32) | (unsigned)bestIdx;
    atomicMin(&best[p], pk);
}

__global__ __launch_bounds__(256) void onehot_kernel(
    const unsigned long long* __restrict__ best, float* __restrict__ out)
{
    int p = blockIdx.x * 256 + threadIdx.x;
    if (p >= NPIXT) return;
    int code = (int)(unsigned)(best[p] & 0xffffffffu);
    int b  = p / HW3;
    int hw = p - b * HW3;
    out[((size_t)b * NEMB + code) * HW3 + hw] = 1.0f;
}

extern "C" void kernel_launch(void* const* d_in, const int* in_sizes, int n_in,
                              void* d_out, int out_size, void* d_ws, size_t ws_size,
                              hipStream_t stream) {
    const float* x  = (const float*)d_in[0];
    const float* w1 = (const float*)d_in[1];
    const float* b1 = (const float*)d_in[2];
    const float* w2 = (const float*)d_in[3];
    const float* b2 = (const float*)d_in[4];
    const float* w3 = (const float*)d_in[5];
    const float* b3 = (const float*)d_in[6];
    const float* cb = (const float*)d_in[7];
    float* out = (float*)d_out;

    float* z1t = (float*)d_ws;                            // [64][294912]  = 75.5 MB
    float* z2t = z1t + (size_t)64 * 294912;               // [128][32768]  = 16.8 MB
    float* z3t = z2t + (size_t)128 * 32768;               // [64][21632]   =  5.5 MB
    unsigned long long* best = (unsigned long long*)(z3t + (size_t)EMB * NPIXT);
    float* w1t = (float*)(best + NPIXT);                  // [192][64]
    float* w2t = w1t + 192 * 64;                          // [2304][128]
    float* w3t = w2t + 2304 * 128;                        // [2048][64]

    hipMemsetAsync(out, 0, (size_t)out_size * sizeof(float), stream);
    hipMemsetAsync(best, 0xFF, (size_t)NPIXT * sizeof(unsigned long long), stream);

    wtrans_kernel<<<(64 * 192 + 255) / 256, 256, 0, stream>>>(w1, w1t, 64, 192);
    wtrans_kernel<<<(128 * 2304 + 255) / 256, 256, 0, stream>>>(w2, w2t, 128, 2304);
    wtrans_kernel<<<(64 * 2048 + 255) / 256, 256, 0, stream>>>(w3, w3t, 64, 2048);

    // conv1: x [n][3][192][192] -> z1t [64][294912]; 294912/128 px = 2304 blocks
    conv_tn<3, 64, 8, 8, 192, 192, 48, 48, 4, 2, true,
            3 * 192 * 192, 192 * 192, 294912, 16>
        <<<294912 / 128, 512, 0, stream>>>(x, w1t, b1, z1t);
    // conv2: z1t ic-major -> z2t [128][32768]; 32768/64 px = 512 blocks
    conv_tn<64, 128, 6, 6, 48, 48, 16, 16, 3, 2, true,
            48 * 48, 294912, 32768, 16>
        <<<32768 / 64, 512, 0, stream>>>(z1t, w2t, b2, z2t);
    // conv3: z2t ic-major -> z3t [64][21632]; 21632/32 px = 676 blocks
    conv_tn<128, 64, 4, 4, 16, 16, 13, 13, 1, 0, false,
            16 * 16, 32768, NPIXT, 4>
        <<<NPIXT / 32, 512, 0, stream>>>(z2t, w3t, b3, z3t);

    vq_kernel<<<338 * 2, 256, 0, stream>>>(z3t, cb, best);
    onehot_kernel<<<(NPIXT + 255) / 256, 256, 0, stream>>>(best, out);
}

// Round 10
// 718.119 us; speedup vs baseline: 1.1897x; 1.1897x over previous
//
#include <hip/hip_runtime.h>
#include <cstdint>
#include <cfloat>

// ---------------------------------------------------------------------------
// SimpleVQVAEEncoder, round 12: R6 base (663 µs) + ONE change: TLP probe.
// conv1/conv2 run as 256-thread (4-wave) blocks instead of 512-thread:
// 2048 thr/CU / 256 = up to 8 resident WGs (finer packing than 4x512,
// observed ~2x512). Per-thread FMA work and per-wave s_load stream are
// IDENTICAL to R6 (NOC=16); only residency granularity changes.
// conv2 adds OCSPLIT=2 (64 oc per block) -> tile staged twice; staging is
// the cheap R3 form (~7 VALU/elem) so cost ~+10 µs, FETCH 54->~105 MB
// (L3-absorbed, proven harmless in R8). conv3/vq/onehot byte-identical R6.
// R1/R4/R5/R9 lessons: no pipelining, no LDS pointers, no broadcast-float4
// LDS reads — plain sync->stage->sync->FMA with direct As[][] indexing.
// ---------------------------------------------------------------------------

constexpr int B_    = 128;
constexpr int HW3   = 169;
constexpr int NPIXT = B_ * HW3;        // 21632
constexpr int NEMB  = 512;
constexpr int EMB   = 64;

// transpose weights [OC][K] -> [K][OC] (tiny prepass)
__global__ __launch_bounds__(256) void wtrans_kernel(
    const float* __restrict__ w, float* __restrict__ wt, int OC, int K)
{
    int idx = blockIdx.x * 256 + threadIdx.x;
    if (idx >= OC * K) return;
    int oc = idx / K, k = idx - oc * K;
    wt[(size_t)k * OC + oc] = w[idx];
}

template<int IC, int OC, int KH, int KW, int IH, int IW, int OH, int OW,
         int STRIDE, int PAD, bool RELU, bool TRANSOUT, int OCSPLIT, int WAVES>
__global__ __launch_bounds__(WAVES * 64) void conv_sgemm(
    const float* __restrict__ in, const float* __restrict__ wt,   // wt: [K][OC]
    const float* __restrict__ bias, float* __restrict__ out)
{
    constexpr int K   = IC * KH * KW;
    constexpr int KHW = KH * KW;
    constexpr int BK  = 64;
    static_assert(K % BK == 0, "K must divide by BK");  // 192/2304/2048: ok
    constexpr int NR  = BK / WAVES;        // rows staged per wave
    constexpr int NOC = OC / OCSPLIT / WAVES;  // accs per thread
    constexpr int HWo = OH * OW;

    __shared__ float As[BK][64];       // 16 KB; b32 reads: 2-way = free

    const int tid  = threadIdx.x;
    const int lane = tid & 63;
    const int wv   = __builtin_amdgcn_readfirstlane(tid >> 6);  // force uniform
    const int osp  = blockIdx.x % OCSPLIT;
    const int oc0  = osp * (OC / OCSPLIT) + wv * NOC;
    const int pixbase = (blockIdx.x / OCSPLIT) * 64;
    const int krow = wv * NR;              // wave-uniform LDS row base

    // ---- hoisted pixel decomposition (lane-dependent only, once) ----
    const int pix = pixbase + lane;
    const int n   = pix / HWo;
    const int hw  = pix - n * HWo;
    const int oy  = hw / OW;
    const int ox  = hw - oy * OW;
    const int iyb = oy * STRIDE - PAD;
    const int ixb = ox * STRIDE - PAD;
    const float* inb = in + (size_t)n * (IC * IH * IW);

    float acc[NOC];
#pragma unroll
    for (int j = 0; j < NOC; j++) acc[j] = 0.f;

    for (int k0 = 0; k0 < K; k0 += BK) {
        __syncthreads();               // previous iter's reads done
#pragma unroll
        for (int i = 0; i < NR; i++) {
            int kk = krow + i;                   // wave-uniform row
            int k  = k0 + kk;                    // uniform
            int ic = k / KHW;                    // uniform -> SALU
            int r  = k - ic * KHW;
            int ky = r / KW;
            int kx = r - ky * KW;
            int iy = iyb + ky;                   // per-lane: 1 add
            int ix = ixb + kx;                   // 1 add
            int off = (ic * IH + iy) * IW + ix;  // mad (ic*IH uniform)
            float v = 0.f;
            if ((unsigned)iy < (unsigned)IH && (unsigned)ix < (unsigned)IW)
                v = inb[off];                    // exec-masked load
            As[kk][lane] = v;
        }
        __syncthreads();

        const float* bp = wt + (size_t)k0 * OC + oc0;    // wave-uniform address
#pragma unroll
        for (int kk = 0; kk < BK; kk++) {
            float a = As[kk][lane];
#pragma unroll
            for (int j = 0; j < NOC; j++)
                acc[j] = fmaf(a, bp[kk * OC + j], acc[j]);   // s_load + v_fmac(s,v)
        }
    }

    // epilogue: bias (+relu), store
#pragma unroll
    for (int j = 0; j < NOC; j++) {
        int oc  = oc0 + j;
        float v = acc[j] + bias[oc];
        if (RELU) v = fmaxf(v, 0.f);
        if (TRANSOUT) out[(size_t)oc * NPIXT + pix] = v;                 // z3t[oc][pix]
        else          out[((size_t)(n * OC + oc)) * HWo + hw] = v;       // NCHW
    }
}

// ---------------------------------------------------------------------------
// VQ: per pixel argmin over 512 codes of |z|^2 - 2 z.c + |c|^2.
// z transposed [64][21632] -> coalesced loads. Codebook reads wave-uniform.
// ---------------------------------------------------------------------------
__global__ __launch_bounds__(256) void vq_kernel(
    const float* __restrict__ zt,           // [64][21632]
    const float* __restrict__ cb,           // [512][64]
    unsigned long long* __restrict__ best)  // [21632], preset to ~0
{
    const int tid  = threadIdx.x;
    const int lane = tid & 63;
    const int wv   = tid >> 6;
    const int pg   = blockIdx.x >> 1;
    const int half = blockIdx.x & 1;
    const int p    = pg * 64 + lane;        // 338*64 == 21632 exactly

    __shared__ float c2s[256];
    {
        int code = half * 256 + tid;
        const float* c = cb + (size_t)code * EMB;
        float s = 0.f;
#pragma unroll
        for (int j = 0; j < EMB; j += 4) {
            float4 v = *(const float4*)(c + j);
            s = fmaf(v.x, v.x, s); s = fmaf(v.y, v.y, s);
            s = fmaf(v.z, v.z, s); s = fmaf(v.w, v.w, s);
        }
        c2s[tid] = s;
    }
    __syncthreads();

    float zr[EMB];
    float zz = 0.f;
#pragma unroll
    for (int j = 0; j < EMB; j++) {
        float v = zt[(size_t)j * NPIXT + p];
        zr[j] = v;
        zz = fmaf(v, v, zz);
    }

    float bestScore = FLT_MAX;
    int   bestIdx   = 0x7fffffff;
    const int base = half * 256 + wv * 64;
    for (int ci = 0; ci < 64; ci++) {
        int code = __builtin_amdgcn_readfirstlane(base + ci);
        const float* c = cb + (size_t)code * EMB;
        float dot = 0.f;
#pragma unroll
        for (int j = 0; j < EMB; j++) dot = fmaf(zr[j], c[j], dot);
        float score = fmaf(-2.f, dot, zz) + c2s[code - half * 256];
        if (score < bestScore) { bestScore = score; bestIdx = code; }
    }

    unsigned u = __float_as_uint(bestScore);
    u = (bestScore < 0.f) ? ~u : (u | 0x80000000u);
    unsigned long long pk = ((unsigned long long)u << 32) | (unsigned)bestIdx;
    atomicMin(&best[p], pk);
}

__global__ __launch_bounds__(256) void onehot_kernel(
    const unsigned long long* __restrict__ best, float* __restrict__ out)
{
    int p = blockIdx.x * 256 + threadIdx.x;
    if (p >= NPIXT) return;
    int code = (int)(unsigned)(best[p] & 0xffffffffu);
    int b  = p / HW3;
    int hw = p - b * HW3;
    out[((size_t)b * NEMB + code) * HW3 + hw] = 1.0f;
}

extern "C" void kernel_launch(void* const* d_in, const int* in_sizes, int n_in,
                              void* d_out, int out_size, void* d_ws, size_t ws_size,
                              hipStream_t stream) {
    const float* x  = (const float*)d_in[0];
    const float* w1 = (const float*)d_in[1];
    const float* b1 = (const float*)d_in[2];
    const float* w2 = (const float*)d_in[3];
    const float* b2 = (const float*)d_in[4];
    const float* w3 = (const float*)d_in[5];
    const float* b3 = (const float*)d_in[6];
    const float* cb = (const float*)d_in[7];
    float* out = (float*)d_out;

    float* z1  = (float*)d_ws;                            // 128*64*48*48   = 75.5 MB
    float* z2  = z1 + (size_t)128 * 64 * 48 * 48;         // 128*128*16*16  = 16.8 MB
    float* z3t = z2 + (size_t)128 * 128 * 16 * 16;        // [64][21632]    =  5.5 MB
    unsigned long long* best = (unsigned long long*)(z3t + (size_t)EMB * NPIXT);
    float* w1t = (float*)(best + NPIXT);                  // [192][64]
    float* w2t = w1t + 192 * 64;                          // [2304][128]
    float* w3t = w2t + 2304 * 128;                        // [2048][64]

    hipMemsetAsync(out, 0, (size_t)out_size * sizeof(float), stream);
    hipMemsetAsync(best, 0xFF, (size_t)NPIXT * sizeof(unsigned long long), stream);

    wtrans_kernel<<<(64 * 192 + 255) / 256, 256, 0, stream>>>(w1, w1t, 64, 192);
    wtrans_kernel<<<(128 * 2304 + 255) / 256, 256, 0, stream>>>(w2, w2t, 128, 2304);
    wtrans_kernel<<<(64 * 2048 + 255) / 256, 256, 0, stream>>>(w3, w3t, 64, 2048);

    // conv1: 4-wave blocks, 4608 blocks; per-thread work identical to R6
    conv_sgemm<3, 64, 8, 8, 192, 192, 48, 48, 4, 2, true, false, 1, 4>
        <<<294912 / 64, 256, 0, stream>>>(x, w1t, b1, z1);
    // conv2: 4-wave blocks x OCSPLIT=2 -> 1024 blocks; NOC=16 (same s_load
    // stream per wave as R6), tile staged twice (cheap staging, L3-absorbed)
    conv_sgemm<64, 128, 6, 6, 48, 48, 16, 16, 3, 2, true, false, 2, 4>
        <<<(32768 / 64) * 2, 256, 0, stream>>>(z1, w2t, b2, z2);
    // conv3: unchanged R6 config — 8-wave blocks, OCSPLIT=2, 676 blocks
    conv_sgemm<128, 64, 4, 4, 16, 16, 13, 13, 1, 0, false, true, 2, 8>
        <<<(NPIXT / 64) * 2, 512, 0, stream>>>(z2, w3t, b3, z3t);

    vq_kernel<<<338 * 2, 256, 0, stream>>>(z3t, cb, best);
    onehot_kernel<<<(NPIXT + 255) / 256, 256, 0, stream>>>(best, out);
}

// Round 11
// 684.568 us; speedup vs baseline: 1.2480x; 1.0490x over previous
//
#include <hip/hip_runtime.h>
#include <cstdint>
#include <cfloat>

// ---------------------------------------------------------------------------
// SimpleVQVAEEncoder, round 13: conv2 -> classic 4x4 register-blocked SGEMM.
// Ten rounds of evidence: the conv loop stalls on the wave-uniform s_load
// weight stream (scalar cache convoy; SGPR-capped prefetch). TLP (R2/R10),
// ILP (R8), pipelining (R1/R4/R5), barrier amortization (R6-BK) all failed.
// Fix: remove scalar loads from the K-loop entirely. Per kk per lane:
//   ds_read_b128 A (4 px)  + ds_read_b128 B (4 oc)  + 16 v_fmac
// A-read: 16 unique 16B segments/wave, 2 segs/bank-quad = 2-way = free.
// B-read: 4 unique segments, 16-lane same-address broadcast = free.
// LDS pipe ~8 cyc per 32 FMA-cyc per wave -> 4x headroom (R9 had 5 DS/kk
// and drowned). Weights staged LDS once per K-step via coalesced float4.
// 48 KB LDS, no scalar pressure -> 3 blocks/CU. conv1/conv3 = R6 exactly.
// No LDS pointers, no runtime buffer indices, 2-barrier skeleton verbatim.
// ---------------------------------------------------------------------------

constexpr int B_    = 128;
constexpr int HW3   = 169;
constexpr int NPIXT = B_ * HW3;        // 21632
constexpr int NEMB  = 512;
constexpr int EMB   = 64;

// transpose weights [OC][K] -> [K][OC] (tiny prepass)
__global__ __launch_bounds__(256) void wtrans_kernel(
    const float* __restrict__ w, float* __restrict__ wt, int OC, int K)
{
    int idx = blockIdx.x * 256 + threadIdx.x;
    if (idx >= OC * K) return;
    int oc = idx / K, k = idx - oc * K;
    wt[(size_t)k * OC + oc] = w[idx];
}

// ---------------- R6 scalar-broadcast kernel (conv1 / conv3) ----------------
template<int IC, int OC, int KH, int KW, int IH, int IW, int OH, int OW,
         int STRIDE, int PAD, bool RELU, bool TRANSOUT, int OCSPLIT>
__global__ __launch_bounds__(512) void conv_sgemm(
    const float* __restrict__ in, const float* __restrict__ wt,   // wt: [K][OC]
    const float* __restrict__ bias, float* __restrict__ out)
{
    constexpr int K   = IC * KH * KW;
    constexpr int KHW = KH * KW;
    constexpr int BK  = 64;
    static_assert(K % BK == 0, "K must divide by BK");
    constexpr int NR  = BK / 8;            // rows staged per wave (8)
    constexpr int NOC = OC / OCSPLIT / 8;  // accs per thread
    constexpr int HWo = OH * OW;

    __shared__ float As[BK][64];       // 16 KB; b32 reads: 2-way = free

    const int tid  = threadIdx.x;
    const int lane = tid & 63;
    const int wv   = __builtin_amdgcn_readfirstlane(tid >> 6);  // force uniform
    const int osp  = blockIdx.x % OCSPLIT;
    const int oc0  = osp * (OC / OCSPLIT) + wv * NOC;
    const int pixbase = (blockIdx.x / OCSPLIT) * 64;
    const int krow = wv * NR;              // wave-uniform LDS row base

    const int pix = pixbase + lane;
    const int n   = pix / HWo;
    const int hw  = pix - n * HWo;
    const int oy  = hw / OW;
    const int ox  = hw - oy * OW;
    const int iyb = oy * STRIDE - PAD;
    const int ixb = ox * STRIDE - PAD;
    const float* inb = in + (size_t)n * (IC * IH * IW);

    float acc[NOC];
#pragma unroll
    for (int j = 0; j < NOC; j++) acc[j] = 0.f;

    for (int k0 = 0; k0 < K; k0 += BK) {
        __syncthreads();
#pragma unroll
        for (int i = 0; i < NR; i++) {
            int kk = krow + i;                   // wave-uniform row
            int k  = k0 + kk;                    // uniform
            int ic = k / KHW;                    // uniform -> SALU
            int r  = k - ic * KHW;
            int ky = r / KW;
            int kx = r - ky * KW;
            int iy = iyb + ky;
            int ix = ixb + kx;
            int off = (ic * IH + iy) * IW + ix;
            float v = 0.f;
            if ((unsigned)iy < (unsigned)IH && (unsigned)ix < (unsigned)IW)
                v = inb[off];
            As[kk][lane] = v;
        }
        __syncthreads();

        const float* bp = wt + (size_t)k0 * OC + oc0;    // wave-uniform address
#pragma unroll
        for (int kk = 0; kk < BK; kk++) {
            float a = As[kk][lane];
#pragma unroll
            for (int j = 0; j < NOC; j++)
                acc[j] = fmaf(a, bp[kk * OC + j], acc[j]);
        }
    }

#pragma unroll
    for (int j = 0; j < NOC; j++) {
        int oc  = oc0 + j;
        float v = acc[j] + bias[oc];
        if (RELU) v = fmaxf(v, 0.f);
        if (TRANSOUT) out[(size_t)oc * NPIXT + pix] = v;
        else          out[((size_t)(n * OC + oc)) * HWo + hw] = v;
    }
}

// ---------------- 4x4 register-blocked kernel (conv2) ----------------------
// Block: 512 thr, tile 64 px x OC. Wave = 16 px-quads x 4 oc-quads;
// wave w owns ocs [w*16, w*16+16). Per lane: 4 px x 4 oc accumulators.
template<int IC, int OC, int KH, int KW, int IH, int IW, int OH, int OW,
         int STRIDE, int PAD, bool RELU>
__global__ __launch_bounds__(512) void conv_rb(
    const float* __restrict__ in, const float* __restrict__ wt,   // wt: [K][OC]
    const float* __restrict__ bias, float* __restrict__ out)
{
    constexpr int K   = IC * KH * KW;
    constexpr int KHW = KH * KW;
    constexpr int BK  = 64;
    static_assert(K % BK == 0 && OC == 128, "conv2 geometry");
    constexpr int HWo = OH * OW;

    __shared__ float As[BK][64];       // 16 KB pixel tile
    __shared__ float Ws[BK * OC];      // 32 KB weight tile [kk][oc]

    const int tid  = threadIdx.x;
    const int lane = tid & 63;
    const int wv   = __builtin_amdgcn_readfirstlane(tid >> 6);  // uniform
    const int pxq  = lane >> 2;            // 0..15
    const int oc0  = wv * 16 + (lane & 3) * 4;
    const int pixbase = blockIdx.x * 64;
    const int krow = wv * 8;               // wave-uniform staging row base

    // staging pixel decomposition (lane = staged pixel), hoisted
    const int pix = pixbase + lane;
    const int n   = pix / HWo;
    const int hw  = pix - n * HWo;
    const int oy  = hw / OW;
    const int ox  = hw - oy * OW;
    const int iyb = oy * STRIDE - PAD;
    const int ixb = ox * STRIDE - PAD;
    const float* inb = in + (size_t)n * (IC * IH * IW);

    float acc[4][4];
#pragma unroll
    for (int p = 0; p < 4; p++)
#pragma unroll
        for (int o = 0; o < 4; o++) acc[p][o] = 0.f;

    for (int k0 = 0; k0 < K; k0 += BK) {
        __syncthreads();
        // ---- stage pixel tile (R6 staging verbatim) ----
#pragma unroll
        for (int i = 0; i < 8; i++) {
            int kk = krow + i;
            int k  = k0 + kk;
            int ic = k / KHW;
            int r  = k - ic * KHW;
            int ky = r / KW;
            int kx = r - ky * KW;
            int iy = iyb + ky;
            int ix = ixb + kx;
            int off = (ic * IH + iy) * IW + ix;
            float v = 0.f;
            if ((unsigned)iy < (unsigned)IH && (unsigned)ix < (unsigned)IW)
                v = inb[off];
            As[kk][lane] = v;
        }
        // ---- stage weight tile, coalesced float4 (L2-resident source) ----
        {
            const float4* wt4 = (const float4*)(wt + (size_t)k0 * OC);
#pragma unroll
            for (int s = 0; s < (BK * OC) / 2048; s++) {   // 4 per thread
                float4 v = wt4[s * 512 + tid];
                *(float4*)&Ws[(s * 512 + tid) * 4] = v;
            }
        }
        __syncthreads();

        // ---- 4x4 outer-product: 2 ds_read_b128 + 16 v_fmac per kk ----
#pragma unroll
        for (int kk = 0; kk < BK; kk++) {
            float4 av = *(const float4*)&As[kk][pxq * 4];
            float4 bv = *(const float4*)&Ws[kk * OC + oc0];
            acc[0][0] = fmaf(av.x, bv.x, acc[0][0]);
            acc[0][1] = fmaf(av.x, bv.y, acc[0][1]);
            acc[0][2] = fmaf(av.x, bv.z, acc[0][2]);
            acc[0][3] = fmaf(av.x, bv.w, acc[0][3]);
            acc[1][0] = fmaf(av.y, bv.x, acc[1][0]);
            acc[1][1] = fmaf(av.y, bv.y, acc[1][1]);
            acc[1][2] = fmaf(av.y, bv.z, acc[1][2]);
            acc[1][3] = fmaf(av.y, bv.w, acc[1][3]);
            acc[2][0] = fmaf(av.z, bv.x, acc[2][0]);
            acc[2][1] = fmaf(av.z, bv.y, acc[2][1]);
            acc[2][2] = fmaf(av.z, bv.z, acc[2][2]);
            acc[2][3] = fmaf(av.z, bv.w, acc[2][3]);
            acc[3][0] = fmaf(av.w, bv.x, acc[3][0]);
            acc[3][1] = fmaf(av.w, bv.y, acc[3][1]);
            acc[3][2] = fmaf(av.w, bv.z, acc[3][2]);
            acc[3][3] = fmaf(av.w, bv.w, acc[3][3]);
        }
    }

    // ---- epilogue: 4 px x 4 oc, bias (+relu), NCHW stores ----
    float4 bv = *(const float4*)&bias[oc0];
    float bb[4] = {bv.x, bv.y, bv.z, bv.w};
#pragma unroll
    for (int p = 0; p < 4; p++) {
        int pixp = pixbase + pxq * 4 + p;
        int np   = pixp / HWo;
        int hwp  = pixp - np * HWo;
#pragma unroll
        for (int o = 0; o < 4; o++) {
            float v = acc[p][o] + bb[o];
            if (RELU) v = fmaxf(v, 0.f);
            out[((size_t)(np * OC + oc0 + o)) * HWo + hwp] = v;
        }
    }
}

// ---------------------------------------------------------------------------
// VQ: per pixel argmin over 512 codes of |z|^2 - 2 z.c + |c|^2.
// ---------------------------------------------------------------------------
__global__ __launch_bounds__(256) void vq_kernel(
    const float* __restrict__ zt,           // [64][21632]
    const float* __restrict__ cb,           // [512][64]
    unsigned long long* __restrict__ best)  // [21632], preset to ~0
{
    const int tid  = threadIdx.x;
    const int lane = tid & 63;
    const int wv   = tid >> 6;
    const int pg   = blockIdx.x >> 1;
    const int half = blockIdx.x & 1;
    const int p    = pg * 64 + lane;        // 338*64 == 21632 exactly

    __shared__ float c2s[256];
    {
        int code = half * 256 + tid;
        const float* c = cb + (size_t)code * EMB;
        float s = 0.f;
#pragma unroll
        for (int j = 0; j < EMB; j += 4) {
            float4 v = *(const float4*)(c + j);
            s = fmaf(v.x, v.x, s); s = fmaf(v.y, v.y, s);
            s = fmaf(v.z, v.z, s); s = fmaf(v.w, v.w, s);
        }
        c2s[tid] = s;
    }
    __syncthreads();

    float zr[EMB];
    float zz = 0.f;
#pragma unroll
    for (int j = 0; j < EMB; j++) {
        float v = zt[(size_t)j * NPIXT + p];
        zr[j] = v;
        zz = fmaf(v, v, zz);
    }

    float bestScore = FLT_MAX;
    int   bestIdx   = 0x7fffffff;
    const int base = half * 256 + wv * 64;
    for (int ci = 0; ci < 64; ci++) {
        int code = __builtin_amdgcn_readfirstlane(base + ci);
        const float* c = cb + (size_t)code * EMB;
        float dot = 0.f;
#pragma unroll
        for (int j = 0; j < EMB; j++) dot = fmaf(zr[j], c[j], dot);
        float score = fmaf(-2.f, dot, zz) + c2s[code - half * 256];
        if (score < bestScore) { bestScore = score; bestIdx = code; }
    }

    unsigned u = __float_as_uint(bestScore);
    u = (bestScore < 0.f) ? ~u : (u | 0x80000000u);
    unsigned long long pk = ((unsigned long long)u << 32) | (unsigned)bestIdx;
    atomicMin(&best[p], pk);
}

__global__ __launch_bounds__(256) void onehot_kernel(
    const unsigned long long* __restrict__ best, float* __restrict__ out)
{
    int p = blockIdx.x * 256 + threadIdx.x;
    if (p >= NPIXT) return;
    int code = (int)(unsigned)(best[p] & 0xffffffffu);
    int b  = p / HW3;
    int hw = p - b * HW3;
    out[((size_t)b * NEMB + code) * HW3 + hw] = 1.0f;
}

extern "C" void kernel_launch(void* const* d_in, const int* in_sizes, int n_in,
                              void* d_out, int out_size, void* d_ws, size_t ws_size,
                              hipStream_t stream) {
    const float* x  = (const float*)d_in[0];
    const float* w1 = (const float*)d_in[1];
    const float* b1 = (const float*)d_in[2];
    const float* w2 = (const float*)d_in[3];
    const float* b2 = (const float*)d_in[4];
    const float* w3 = (const float*)d_in[5];
    const float* b3 = (const float*)d_in[6];
    const float* cb = (const float*)d_in[7];
    float* out = (float*)d_out;

    float* z1  = (float*)d_ws;                            // 128*64*48*48   = 75.5 MB
    float* z2  = z1 + (size_t)128 * 64 * 48 * 48;         // 128*128*16*16  = 16.8 MB
    float* z3t = z2 + (size_t)128 * 128 * 16 * 16;        // [64][21632]    =  5.5 MB
    unsigned long long* best = (unsigned long long*)(z3t + (size_t)EMB * NPIXT);
    float* w1t = (float*)(best + NPIXT);                  // [192][64]
    float* w2t = w1t + 192 * 64;                          // [2304][128]
    float* w3t = w2t + 2304 * 128;                        // [2048][64]

    hipMemsetAsync(out, 0, (size_t)out_size * sizeof(float), stream);
    hipMemsetAsync(best, 0xFF, (size_t)NPIXT * sizeof(unsigned long long), stream);

    wtrans_kernel<<<(64 * 192 + 255) / 256, 256, 0, stream>>>(w1, w1t, 64, 192);
    wtrans_kernel<<<(128 * 2304 + 255) / 256, 256, 0, stream>>>(w2, w2t, 128, 2304);
    wtrans_kernel<<<(64 * 2048 + 255) / 256, 256, 0, stream>>>(w3, w3t, 64, 2048);

    // conv1: R6 config — 4608 blocks, 8-wave, scalar-broadcast
    conv_sgemm<3, 64, 8, 8, 192, 192, 48, 48, 4, 2, true, false, 1>
        <<<294912 / 64, 512, 0, stream>>>(x, w1t, b1, z1);
    // conv2: 4x4 register-blocked, 512 blocks, no scalar loads in K-loop
    conv_rb<64, 128, 6, 6, 48, 48, 16, 16, 3, 2, true>
        <<<32768 / 64, 512, 0, stream>>>(z1, w2t, b2, z2);
    // conv3: R6 config — OCSPLIT=2, 676 blocks, transposed out
    conv_sgemm<128, 64, 4, 4, 16, 16, 13, 13, 1, 0, false, true, 2>
        <<<(NPIXT / 64) * 2, 512, 0, stream>>>(z2, w3t, b3, z3t);

    vq_kernel<<<338 * 2, 256, 0, stream>>>(z3t, cb, best);
    onehot_kernel<<<(NPIXT + 255) / 256, 256, 0, stream>>>(best, out);
}

// Round 12
// 663.818 us; speedup vs baseline: 1.2870x; 1.0313x over previous
//
#include <hip/hip_runtime.h>
#include <cstdint>
#include <cfloat>

// ---------------------------------------------------------------------------
// SimpleVQVAEEncoder, round 14: lock the convs at the R6 champion configs
// (11 rounds of evidence: 2-barrier scalar-broadcast BK=64 is the compiler's
// local optimum; all pipelining / 2D-blocking / transposed variants regress),
// and harvest the periphery:
//  - vq + onehot fused: 512-thr blocks, 8 waves x 64 codes = all 512 codes,
//    LDS u64-min reduce (no global atomicMin, no best buffer/memset),
//    block writes the full one-hot slab for its 64 pixels (no out memset,
//    no onehot kernel). Tie-break = smallest index, as before.
//  - 3 wtrans fused into one range-switched kernel.
//  - dispatches 10 -> 5.
// ---------------------------------------------------------------------------

constexpr int B_    = 128;
constexpr int HW3   = 169;
constexpr int NPIXT = B_ * HW3;        // 21632
constexpr int NEMB  = 512;
constexpr int EMB   = 64;

// fused transpose of all three weight tensors [OC][K] -> [K][OC]
__global__ __launch_bounds__(256) void wtrans_all_kernel(
    const float* __restrict__ w1, const float* __restrict__ w2,
    const float* __restrict__ w3,
    float* __restrict__ wt1, float* __restrict__ wt2, float* __restrict__ wt3)
{
    constexpr int S1 = 64 * 192;
    constexpr int S2 = 128 * 2304;
    constexpr int S3 = 64 * 2048;
    int idx = blockIdx.x * 256 + threadIdx.x;
    if (idx < S1) {
        int oc = idx / 192, k = idx - oc * 192;
        wt1[k * 64 + oc] = w1[idx];
    } else if (idx < S1 + S2) {
        int i = idx - S1;
        int oc = i / 2304, k = i - oc * 2304;
        wt2[k * 128 + oc] = w2[i];
    } else if (idx < S1 + S2 + S3) {
        int i = idx - S1 - S2;
        int oc = i / 2048, k = i - oc * 2048;
        wt3[k * 64 + oc] = w3[i];
    }
}

// ---------------- R6 scalar-broadcast conv (champion, untouched) -----------
template<int IC, int OC, int KH, int KW, int IH, int IW, int OH, int OW,
         int STRIDE, int PAD, bool RELU, bool TRANSOUT, int OCSPLIT>
__global__ __launch_bounds__(512) void conv_sgemm(
    const float* __restrict__ in, const float* __restrict__ wt,   // wt: [K][OC]
    const float* __restrict__ bias, float* __restrict__ out)
{
    constexpr int K   = IC * KH * KW;
    constexpr int KHW = KH * KW;
    constexpr int BK  = 64;
    static_assert(K % BK == 0, "K must divide by BK");
    constexpr int NR  = BK / 8;            // rows staged per wave (8)
    constexpr int NOC = OC / OCSPLIT / 8;  // accs per thread
    constexpr int HWo = OH * OW;

    __shared__ float As[BK][64];       // 16 KB; b32 reads: 2-way = free

    const int tid  = threadIdx.x;
    const int lane = tid & 63;
    const int wv   = __builtin_amdgcn_readfirstlane(tid >> 6);  // force uniform
    const int osp  = blockIdx.x % OCSPLIT;
    const int oc0  = osp * (OC / OCSPLIT) + wv * NOC;
    const int pixbase = (blockIdx.x / OCSPLIT) * 64;
    const int krow = wv * NR;              // wave-uniform LDS row base

    const int pix = pixbase + lane;
    const int n   = pix / HWo;
    const int hw  = pix - n * HWo;
    const int oy  = hw / OW;
    const int ox  = hw - oy * OW;
    const int iyb = oy * STRIDE - PAD;
    const int ixb = ox * STRIDE - PAD;
    const float* inb = in + (size_t)n * (IC * IH * IW);

    float acc[NOC];
#pragma unroll
    for (int j = 0; j < NOC; j++) acc[j] = 0.f;

    for (int k0 = 0; k0 < K; k0 += BK) {
        __syncthreads();
#pragma unroll
        for (int i = 0; i < NR; i++) {
            int kk = krow + i;                   // wave-uniform row
            int k  = k0 + kk;                    // uniform
            int ic = k / KHW;                    // uniform -> SALU
            int r  = k - ic * KHW;
            int ky = r / KW;
            int kx = r - ky * KW;
            int iy = iyb + ky;
            int ix = ixb + kx;
            int off = (ic * IH + iy) * IW + ix;
            float v = 0.f;
            if ((unsigned)iy < (unsigned)IH && (unsigned)ix < (unsigned)IW)
                v = inb[off];
            As[kk][lane] = v;
        }
        __syncthreads();

        const float* bp = wt + (size_t)k0 * OC + oc0;    // wave-uniform address
#pragma unroll
        for (int kk = 0; kk < BK; kk++) {
            float a = As[kk][lane];
#pragma unroll
            for (int j = 0; j < NOC; j++)
                acc[j] = fmaf(a, bp[kk * OC + j], acc[j]);   // s_load + v_fmac
        }
    }

#pragma unroll
    for (int j = 0; j < NOC; j++) {
        int oc  = oc0 + j;
        float v = acc[j] + bias[oc];
        if (RELU) v = fmaxf(v, 0.f);
        if (TRANSOUT) out[(size_t)oc * NPIXT + pix] = v;
        else          out[((size_t)(n * OC + oc)) * HWo + hw] = v;
    }
}

// ---------------- fused VQ + one-hot ---------------------------------------
// 338 blocks x 512 thr. Block owns 64 pixels (lane) x ALL 512 codes
// (wave wv scans codes wv*64..wv*64+63). LDS u64-min across waves; every
// (pixel, code) cell of the output written exactly once (0 or 1) -> no
// out memset, no best buffer, no separate onehot kernel.
__global__ __launch_bounds__(512) void vq_onehot_kernel(
    const float* __restrict__ zt,           // [64][21632]
    const float* __restrict__ cb,           // [512][64]
    float* __restrict__ out)                // [128][512][169]
{
    const int tid  = threadIdx.x;
    const int lane = tid & 63;
    const int wv   = tid >> 6;              // 0..7
    const int p    = blockIdx.x * 64 + lane;
    const int b    = p / HW3;
    const int hw   = p - b * HW3;

    __shared__ float c2s[NEMB];             // 2 KB
    __shared__ unsigned long long red[8][64];  // 4 KB
    __shared__ int bestc[64];

    // |c|^2 for all 512 codes: one code per thread
    {
        const float* c = cb + (size_t)tid * EMB;
        float s = 0.f;
#pragma unroll
        for (int j = 0; j < EMB; j += 4) {
            float4 v = *(const float4*)(c + j);
            s = fmaf(v.x, v.x, s); s = fmaf(v.y, v.y, s);
            s = fmaf(v.z, v.z, s); s = fmaf(v.w, v.w, s);
        }
        c2s[tid] = s;
    }
    __syncthreads();

    // pixel vector in registers (all 8 waves load the same 64 pixels; L2-hot)
    float zr[EMB];
    float zz = 0.f;
#pragma unroll
    for (int j = 0; j < EMB; j++) {
        float v = zt[(size_t)j * NPIXT + p];
        zr[j] = v;
        zz = fmaf(v, v, zz);
    }

    // wave-local argmin over this wave's 64 codes (codebook reads uniform)
    float bestScore = FLT_MAX;
    int   bestIdx   = 0x7fffffff;
    const int base = wv * 64;
    for (int ci = 0; ci < 64; ci++) {
        int code = __builtin_amdgcn_readfirstlane(base + ci);
        const float* c = cb + (size_t)code * EMB;
        float dot = 0.f;
#pragma unroll
        for (int j = 0; j < EMB; j++) dot = fmaf(zr[j], c[j], dot);
        float score = fmaf(-2.f, dot, zz) + c2s[code];
        if (score < bestScore) { bestScore = score; bestIdx = code; }
    }

    unsigned u = __float_as_uint(bestScore);
    u = (bestScore < 0.f) ? ~u : (u | 0x80000000u);
    red[wv][lane] = ((unsigned long long)u << 32) | (unsigned)bestIdx;
    __syncthreads();

    // cross-wave reduce (wave 0), tie-break = smallest index via u64 min
    if (wv == 0) {
        unsigned long long m = red[0][lane];
#pragma unroll
        for (int w = 1; w < 8; w++) {
            unsigned long long v = red[w][lane];
            m = (v < m) ? v : m;
        }
        bestc[lane] = (int)(unsigned)(m & 0xffffffffu);
    }
    __syncthreads();

    // write the full one-hot slab: wave wv writes its 64 codes for all
    // 64 pixels; per iteration lanes store consecutive hw -> coalesced
    const int mycode = bestc[lane];
    float* ob = out + (size_t)b * (NEMB * HW3) + hw;
    for (int ci = 0; ci < 64; ci++) {
        int code = base + ci;
        ob[(size_t)code * HW3] = (code == mycode) ? 1.0f : 0.0f;
    }
}

extern "C" void kernel_launch(void* const* d_in, const int* in_sizes, int n_in,
                              void* d_out, int out_size, void* d_ws, size_t ws_size,
                              hipStream_t stream) {
    const float* x  = (const float*)d_in[0];
    const float* w1 = (const float*)d_in[1];
    const float* b1 = (const float*)d_in[2];
    const float* w2 = (const float*)d_in[3];
    const float* b2 = (const float*)d_in[4];
    const float* w3 = (const float*)d_in[5];
    const float* b3 = (const float*)d_in[6];
    const float* cb = (const float*)d_in[7];
    float* out = (float*)d_out;

    float* z1  = (float*)d_ws;                            // 128*64*48*48   = 75.5 MB
    float* z2  = z1 + (size_t)128 * 64 * 48 * 48;         // 128*128*16*16  = 16.8 MB
    float* z3t = z2 + (size_t)128 * 128 * 16 * 16;        // [64][21632]    =  5.5 MB
    float* w1t = z3t + (size_t)EMB * NPIXT;               // [192][64]
    float* w2t = w1t + 192 * 64;                          // [2304][128]
    float* w3t = w2t + 2304 * 128;                        // [2048][64]

    // all three weight transposes in one dispatch
    constexpr int WT_TOTAL = 64 * 192 + 128 * 2304 + 64 * 2048;
    wtrans_all_kernel<<<(WT_TOTAL + 255) / 256, 256, 0, stream>>>(
        w1, w2, w3, w1t, w2t, w3t);

    // conv1: R6 config — 4608 blocks, 8-wave, scalar-broadcast
    conv_sgemm<3, 64, 8, 8, 192, 192, 48, 48, 4, 2, true, false, 1>
        <<<294912 / 64, 512, 0, stream>>>(x, w1t, b1, z1);
    // conv2: R6 config — 512 blocks, full OC per block
    conv_sgemm<64, 128, 6, 6, 48, 48, 16, 16, 3, 2, true, false, 1>
        <<<32768 / 64, 512, 0, stream>>>(z1, w2t, b2, z2);
    // conv3: R6 config — OCSPLIT=2, 676 blocks, transposed out
    conv_sgemm<128, 64, 4, 4, 16, 16, 13, 13, 1, 0, false, true, 2>
        <<<(NPIXT / 64) * 2, 512, 0, stream>>>(z2, w3t, b3, z3t);

    // fused VQ + one-hot: writes every element of out (no memsets needed)
    vq_onehot_kernel<<<NPIXT / 64, 512, 0, stream>>>(z3t, cb, out);
}

// Round 13
// 520.089 us; speedup vs baseline: 1.6427x; 1.2764x over previous
//
#include <hip/hip_runtime.h>
#include <cstdint>
#include <cfloat>

// ---------------------------------------------------------------------------
// SimpleVQVAEEncoder, round 15: conv2 -> split-fp16 MFMA GEMM.
//   a = ah + al/4096 (al = fp16((a-ah)*4096); scaling keeps the residual
//   above fp16 denormal flush); same for w. acc0 = sum ah*wh (MFMA),
//   acc1 = sum (ah*wl + al*wh); result = acc0 + acc1/4096. Dropped term
//   ~2^-22 relative (~4x fp32 noise; R7 passed with nondet atomics).
//   z1 pre-split in conv1's epilogue (packed u32 h|l<<16); w2 pre-split in
//   the prepass. conv2: 64px x 128oc blocks, 4 waves, each 32px x 64oc via
//   8x mfma_f32_16x16x32_f16 x 3 terms. LDS: half8 arrays, DIRECT indexing
//   only, XOR-swizzled 16B blocks (kb ^ ((row>>1)&3)) for conflict-free
//   ds_read_b128. K-slot mapping identical on A and B sides (permutation
//   cancels). conv1/conv3/vq_onehot remain the champion versions.
// ---------------------------------------------------------------------------

constexpr int B_    = 128;
constexpr int HW3   = 169;
constexpr int NPIXT = B_ * HW3;        // 21632
constexpr int NEMB  = 512;
constexpr int EMB   = 64;

typedef _Float16 half8 __attribute__((ext_vector_type(8)));
typedef float    f32x4 __attribute__((ext_vector_type(4)));

static __device__ inline unsigned short h2u(_Float16 h) {
    union { _Float16 f; unsigned short u; } x; x.f = h; return x.u;
}
static __device__ inline _Float16 u2h(unsigned short u) {
    union { _Float16 f; unsigned short u; } x; x.u = u; return x.f;
}

// fused prepass: w1/w3 transpose [OC][K]->[K][OC] fp32; w2 split to h/l fp16
__global__ __launch_bounds__(256) void prep_kernel(
    const float* __restrict__ w1, const float* __restrict__ w2,
    const float* __restrict__ w3,
    float* __restrict__ wt1, _Float16* __restrict__ w2h,
    _Float16* __restrict__ w2l, float* __restrict__ wt3)
{
    constexpr int S1 = 64 * 192;
    constexpr int S2 = 128 * 2304;
    constexpr int S3 = 64 * 2048;
    int idx = blockIdx.x * 256 + threadIdx.x;
    if (idx < S1) {
        int oc = idx / 192, k = idx - oc * 192;
        wt1[k * 64 + oc] = w1[idx];
    } else if (idx < S1 + S2) {
        int i = idx - S1;
        float v = w2[i];
        _Float16 h = (_Float16)v;
        _Float16 l = (_Float16)((v - (float)h) * 4096.f);
        w2h[i] = h; w2l[i] = l;
    } else if (idx < S1 + S2 + S3) {
        int i = idx - S1 - S2;
        int oc = i / 2048, k = i - oc * 2048;
        wt3[k * 64 + oc] = w3[i];
    }
}

// ---------------- R6 scalar-broadcast conv (conv1 / conv3) -----------------
// PACK: epilogue writes packed u32 (fp16 hi | lo<<16) instead of fp32.
template<int IC, int OC, int KH, int KW, int IH, int IW, int OH, int OW,
         int STRIDE, int PAD, bool RELU, bool TRANSOUT, int OCSPLIT, bool PACK>
__global__ __launch_bounds__(512) void conv_sgemm(
    const float* __restrict__ in, const float* __restrict__ wt,   // wt: [K][OC]
    const float* __restrict__ bias, float* __restrict__ out)
{
    constexpr int K   = IC * KH * KW;
    constexpr int KHW = KH * KW;
    constexpr int BK  = 64;
    static_assert(K % BK == 0, "K must divide by BK");
    constexpr int NR  = BK / 8;
    constexpr int NOC = OC / OCSPLIT / 8;
    constexpr int HWo = OH * OW;

    __shared__ float As[BK][64];

    const int tid  = threadIdx.x;
    const int lane = tid & 63;
    const int wv   = __builtin_amdgcn_readfirstlane(tid >> 6);
    const int osp  = blockIdx.x % OCSPLIT;
    const int oc0  = osp * (OC / OCSPLIT) + wv * NOC;
    const int pixbase = (blockIdx.x / OCSPLIT) * 64;
    const int krow = wv * NR;

    const int pix = pixbase + lane;
    const int n   = pix / HWo;
    const int hw  = pix - n * HWo;
    const int oy  = hw / OW;
    const int ox  = hw - oy * OW;
    const int iyb = oy * STRIDE - PAD;
    const int ixb = ox * STRIDE - PAD;
    const float* inb = in + (size_t)n * (IC * IH * IW);

    float acc[NOC];
#pragma unroll
    for (int j = 0; j < NOC; j++) acc[j] = 0.f;

    for (int k0 = 0; k0 < K; k0 += BK) {
        __syncthreads();
#pragma unroll
        for (int i = 0; i < NR; i++) {
            int kk = krow + i;
            int k  = k0 + kk;                    // uniform -> SALU decomp
            int ic = k / KHW;
            int r  = k - ic * KHW;
            int ky = r / KW;
            int kx = r - ky * KW;
            int iy = iyb + ky;
            int ix = ixb + kx;
            int off = (ic * IH + iy) * IW + ix;
            float v = 0.f;
            if ((unsigned)iy < (unsigned)IH && (unsigned)ix < (unsigned)IW)
                v = inb[off];
            As[kk][lane] = v;
        }
        __syncthreads();

        const float* bp = wt + (size_t)k0 * OC + oc0;
#pragma unroll
        for (int kk = 0; kk < BK; kk++) {
            float a = As[kk][lane];
#pragma unroll
            for (int j = 0; j < NOC; j++)
                acc[j] = fmaf(a, bp[kk * OC + j], acc[j]);
        }
    }

#pragma unroll
    for (int j = 0; j < NOC; j++) {
        int oc  = oc0 + j;
        float v = acc[j] + bias[oc];
        if (RELU) v = fmaxf(v, 0.f);
        if (PACK) {
            _Float16 h = (_Float16)v;
            _Float16 l = (_Float16)((v - (float)h) * 4096.f);
            unsigned u = (unsigned)h2u(h) | ((unsigned)h2u(l) << 16);
            ((unsigned*)out)[((size_t)(n * OC + oc)) * HWo + hw] = u;
        } else if (TRANSOUT) {
            out[(size_t)oc * NPIXT + pix] = v;
        } else {
            out[((size_t)(n * OC + oc)) * HWo + hw] = v;
        }
    }
}

// ---------------- conv2: split-fp16 MFMA GEMM ------------------------------
// 512 blocks x 256 thr. Block = 64 px x 128 oc. Wave wv: px-half (wv&1),
// oc-half (wv>>1); 2x4 tiles of 16x16, K-step 32 (one MFMA k-chunk).
__global__ __launch_bounds__(256) void conv2_mfma(
    const unsigned* __restrict__ z1p,     // [128*64][2304] packed h|l<<16
    const _Float16* __restrict__ w2h,     // [128][2304]
    const _Float16* __restrict__ w2l,
    const float* __restrict__ bias, float* __restrict__ out)  // [n][128][256]
{
    constexpr int K = 2304, KHW = 36, KW = 6, IH = 48, IW = 48;
    __shared__ half8 Ah8[64][4], Al8[64][4];   // [px][kb]  4 KB each
    __shared__ half8 Bh8[128][4], Bl8[128][4]; // [oc][kb]  8 KB each

    const int tid  = threadIdx.x;
    const int lane = tid & 63;
    const int wv   = __builtin_amdgcn_readfirstlane(tid >> 6);  // 0..3
    const int pixbase = blockIdx.x * 64;

    // A-staging decomposition (px = lane), hoisted
    const int pix = pixbase + lane;
    const int n   = pix >> 8;               // HWo = 256
    const int hw  = pix & 255;
    const int oy  = hw >> 4, ox = hw & 15;  // OW = 16
    const int iyb = oy * 3 - 2, ixb = ox * 3 - 2;
    const unsigned* inb = z1p + (size_t)n * (64 * 2304);

    // B-staging mapping
    const int boc = tid >> 2;               // 0..63 (and +64)
    const int bkb = tid & 3;

    f32x4 zero4 = {0.f, 0.f, 0.f, 0.f};
    f32x4 acc0[2][4], acc1[2][4];
#pragma unroll
    for (int p = 0; p < 2; p++)
#pragma unroll
        for (int o = 0; o < 4; o++) { acc0[p][o] = zero4; acc1[p][o] = zero4; }

    for (int t = 0; t < K / 32; t++) {
        const int k0 = t * 32;
        __syncthreads();
        // ---- stage A: this thread owns (px=lane, kgroup=wv) = one half8 pair
        {
            half8 vh, vl;
#pragma unroll
            for (int j = 0; j < 8; j++) {
                int k  = k0 + wv * 8 + j;        // wave-uniform -> SALU decomp
                int ic = k / KHW;
                int r  = k - ic * KHW;
                int ky = r / KW;
                int kx = r - ky * KW;
                int iy = iyb + ky;
                int ix = ixb + kx;
                unsigned pv = 0;
                if ((unsigned)iy < (unsigned)IH && (unsigned)ix < (unsigned)IW)
                    pv = inb[ic * 2304 + iy * 48 + ix];
                vh[j] = u2h((unsigned short)(pv & 0xffffu));
                vl[j] = u2h((unsigned short)(pv >> 16));
            }
            int sw = wv ^ ((lane >> 1) & 3);     // XOR-swizzled 16B block
            Ah8[lane][sw] = vh;
            Al8[lane][sw] = vl;
        }
        // ---- stage B: 2 (oc, kb) slots, coalesced global half8 loads
#pragma unroll
        for (int s = 0; s < 2; s++) {
            int oc = boc + s * 64;
            size_t off = (size_t)oc * K + k0 + bkb * 8;   // 16B-aligned
            int sw = bkb ^ ((oc >> 1) & 3);
            Bh8[oc][sw] = *(const half8*)(w2h + off);
            Bl8[oc][sw] = *(const half8*)(w2l + off);
        }
        __syncthreads();

        // ---- fragments (direct LDS indexing, swizzle matches writes)
        const int row = lane & 15;
        const int kq  = lane >> 4;               // k-block, same map A & B
        half8 fah[2], fal[2], fbh[4], fbl[4];
#pragma unroll
        for (int p = 0; p < 2; p++) {
            int pr = (wv & 1) * 32 + p * 16 + row;
            int sw = kq ^ ((pr >> 1) & 3);
            fah[p] = Ah8[pr][sw];
            fal[p] = Al8[pr][sw];
        }
#pragma unroll
        for (int o = 0; o < 4; o++) {
            int orow = (wv >> 1) * 64 + o * 16 + row;
            int sw = kq ^ ((orow >> 1) & 3);
            fbh[o] = Bh8[orow][sw];
            fbl[o] = Bl8[orow][sw];
        }
#pragma unroll
        for (int p = 0; p < 2; p++)
#pragma unroll
            for (int o = 0; o < 4; o++) {
                acc0[p][o] = __builtin_amdgcn_mfma_f32_16x16x32_f16(
                    fah[p], fbh[o], acc0[p][o], 0, 0, 0);
                acc1[p][o] = __builtin_amdgcn_mfma_f32_16x16x32_f16(
                    fah[p], fbl[o], acc1[p][o], 0, 0, 0);
                acc1[p][o] = __builtin_amdgcn_mfma_f32_16x16x32_f16(
                    fal[p], fbh[o], acc1[p][o], 0, 0, 0);
            }
    }

    // ---- epilogue: D row=(lane>>4)*4+j, col=lane&15 (verified C/D map)
    const int row = lane & 15, rg = lane >> 4;
#pragma unroll
    for (int p = 0; p < 2; p++)
#pragma unroll
        for (int o = 0; o < 4; o++) {
            int oc = (wv >> 1) * 64 + o * 16 + row;
            float b = bias[oc];
#pragma unroll
            for (int j = 0; j < 4; j++) {
                int px = pixbase + (wv & 1) * 32 + p * 16 + rg * 4 + j;
                float v = acc0[p][o][j] + acc1[p][o][j] * (1.f / 4096.f) + b;
                v = fmaxf(v, 0.f);
                int nn = px >> 8, hh = px & 255;
                out[((size_t)(nn * 128 + oc)) * 256 + hh] = v;
            }
        }
}

// ---------------- fused VQ + one-hot (champion) ----------------------------
__global__ __launch_bounds__(512) void vq_onehot_kernel(
    const float* __restrict__ zt,           // [64][21632]
    const float* __restrict__ cb,           // [512][64]
    float* __restrict__ out)                // [128][512][169]
{
    const int tid  = threadIdx.x;
    const int lane = tid & 63;
    const int wv   = tid >> 6;              // 0..7
    const int p    = blockIdx.x * 64 + lane;
    const int b    = p / HW3;
    const int hw   = p - b * HW3;

    __shared__ float c2s[NEMB];
    __shared__ unsigned long long red[8][64];
    __shared__ int bestc[64];

    {
        const float* c = cb + (size_t)tid * EMB;
        float s = 0.f;
#pragma unroll
        for (int j = 0; j < EMB; j += 4) {
            float4 v = *(const float4*)(c + j);
            s = fmaf(v.x, v.x, s); s = fmaf(v.y, v.y, s);
            s = fmaf(v.z, v.z, s); s = fmaf(v.w, v.w, s);
        }
        c2s[tid] = s;
    }
    __syncthreads();

    float zr[EMB];
    float zz = 0.f;
#pragma unroll
    for (int j = 0; j < EMB; j++) {
        float v = zt[(size_t)j * NPIXT + p];
        zr[j] = v;
        zz = fmaf(v, v, zz);
    }

    float bestScore = FLT_MAX;
    int   bestIdx   = 0x7fffffff;
    const int base = wv * 64;
    for (int ci = 0; ci < 64; ci++) {
        int code = __builtin_amdgcn_readfirstlane(base + ci);
        const float* c = cb + (size_t)code * EMB;
        float dot = 0.f;
#pragma unroll
        for (int j = 0; j < EMB; j++) dot = fmaf(zr[j], c[j], dot);
        float score = fmaf(-2.f, dot, zz) + c2s[code];
        if (score < bestScore) { bestScore = score; bestIdx = code; }
    }

    unsigned u = __float_as_uint(bestScore);
    u = (bestScore < 0.f) ? ~u : (u | 0x80000000u);
    red[wv][lane] = ((unsigned long long)u << 32) | (unsigned)bestIdx;
    __syncthreads();

    if (wv == 0) {
        unsigned long long m = red[0][lane];
#pragma unroll
        for (int w = 1; w < 8; w++) {
            unsigned long long v = red[w][lane];
            m = (v < m) ? v : m;
        }
        bestc[lane] = (int)(unsigned)(m & 0xffffffffu);
    }
    __syncthreads();

    const int mycode = bestc[lane];
    float* ob = out + (size_t)b * (NEMB * HW3) + hw;
    for (int ci = 0; ci < 64; ci++) {
        int code = base + ci;
        ob[(size_t)code * HW3] = (code == mycode) ? 1.0f : 0.0f;
    }
}

extern "C" void kernel_launch(void* const* d_in, const int* in_sizes, int n_in,
                              void* d_out, int out_size, void* d_ws, size_t ws_size,
                              hipStream_t stream) {
    const float* x  = (const float*)d_in[0];
    const float* w1 = (const float*)d_in[1];
    const float* b1 = (const float*)d_in[2];
    const float* w2 = (const float*)d_in[3];
    const float* b2 = (const float*)d_in[4];
    const float* w3 = (const float*)d_in[5];
    const float* b3 = (const float*)d_in[6];
    const float* cb = (const float*)d_in[7];
    float* out = (float*)d_out;

    unsigned* z1p = (unsigned*)d_ws;                      // [128*64][2304] u32 = 75.5 MB
    float* z2  = (float*)(z1p + (size_t)128 * 64 * 2304); // 128*128*256 f32 = 16.8 MB
    float* z3t = z2 + (size_t)128 * 128 * 256;            // [64][21632] = 5.5 MB
    float* w1t = z3t + (size_t)EMB * NPIXT;               // [192][64] f32
    float* w3t = w1t + 192 * 64;                          // [2048][64] f32
    _Float16* w2h = (_Float16*)(w3t + 2048 * 64);         // [128][2304] f16
    _Float16* w2l = w2h + (size_t)128 * 2304;             // [128][2304] f16

    constexpr int PTOT = 64 * 192 + 128 * 2304 + 64 * 2048;
    prep_kernel<<<(PTOT + 255) / 256, 256, 0, stream>>>(
        w1, w2, w3, w1t, w2h, w2l, w3t);

    // conv1: champion config, epilogue packs fp16 h/l into z1p
    conv_sgemm<3, 64, 8, 8, 192, 192, 48, 48, 4, 2, true, false, 1, true>
        <<<294912 / 64, 512, 0, stream>>>(x, w1t, b1, (float*)z1p);
    // conv2: split-fp16 MFMA, 512 blocks x 256 thr
    conv2_mfma<<<32768 / 64, 256, 0, stream>>>(z1p, w2h, w2l, b2, z2);
    // conv3: champion config (fp32 path), OCSPLIT=2, transposed out
    conv_sgemm<128, 64, 4, 4, 16, 16, 13, 13, 1, 0, false, true, 2, false>
        <<<(NPIXT / 64) * 2, 512, 0, stream>>>(z2, w3t, b3, z3t);

    vq_onehot_kernel<<<NPIXT / 64, 512, 0, stream>>>(z3t, cb, out);
}